// Round 2
// baseline (252.950 us; speedup 1.0000x reference)
//
#include <hip/hip_runtime.h>

// DigitCaps dynamic routing, B=256 R=192 C=96 O=16 I=20. fp32 in/out.
// u_hat ([256,192,96,16] = 302 MB) is never materialized:
//   s  = Xk[256,3840](bf16) @ WsT[1536,3840](bf16, k-major)   WsT = c[r,c]*W
//   Z  = xT[3840,256](bf16) @ vT[1536,256](bf16, k-major)
//   a[r,c] = (1/256) * sum_{i,o} W[r,c,o,i] * Z[(r,i),(c,o)]

#define R_ 192
#define C_ 96
#define O_ 16
#define I_ 20
#define B_ 256
#define K1 3840   // R*I
#define N_ 1536   // C*O

typedef unsigned short u16;
typedef __attribute__((ext_vector_type(8))) short short8;
typedef __attribute__((ext_vector_type(4))) float floatx4;

__device__ inline float bf2f(u16 h) {
  union { unsigned int u; float f; } x; x.u = ((unsigned int)h) << 16; return x.f;
}
__device__ inline u16 f2bf(float f) {
  union { float f; unsigned int u; } x; x.f = f;
  unsigned int r = x.u + 0x7FFFu + ((x.u >> 16) & 1u);
  return (u16)(r >> 16);
}

// ---- prep: W[r,c,o,i] (fp32) -> WtT[(c*16+o)*3840 + r*20+i] (bf16, k-contig)
__global__ void k_prep_w(const float* __restrict__ W, u16* __restrict__ WtT) {
  int t = blockIdx.x * 256 + threadIdx.x;      // over N_*K1 = 5,898,240
  int n = t / K1, k = t - n * K1;
  int c = n >> 4, o = n & 15;
  int r = k / I_, i = k - r * I_;
  WtT[t] = f2bf(W[(((r * C_ + c) * O_ + o) * I_) + i]);
}

// ---- cast: X fp32 [256,3840] -> Xk bf16 (same layout), 4 elems/thread
__global__ void k_cast_x(const float* __restrict__ X, u16* __restrict__ Xk) {
  int t = blockIdx.x * 256 + threadIdx.x;      // over 245,760
  float4 v = ((const float4*)X)[t];
  ushort4 o;
  o.x = f2bf(v.x); o.y = f2bf(v.y); o.z = f2bf(v.z); o.w = f2bf(v.w);
  ((ushort4*)Xk)[t] = o;
}

// ---- transpose: X[b,k] fp32 -> xT[k*256+b] bf16, 64x64 LDS tiles
__global__ void k_trans_x(const float* __restrict__ X, u16* __restrict__ xT) {
  __shared__ u16 tile[64][72];
  int kb = blockIdx.x << 6, bb = blockIdx.y << 6;
  int brow = threadIdx.x >> 4;          // 0..15
  int kq = (threadIdx.x & 15) << 2;     // 0..60 step 4
  #pragma unroll
  for (int p = 0; p < 4; ++p) {
    int bl = p * 16 + brow;
    float4 v = *(const float4*)(X + (size_t)(bb + bl) * K1 + kb + kq);
    tile[kq + 0][bl] = f2bf(v.x);
    tile[kq + 1][bl] = f2bf(v.y);
    tile[kq + 2][bl] = f2bf(v.z);
    tile[kq + 3][bl] = f2bf(v.w);
  }
  __syncthreads();
  int kr = threadIdx.x >> 3;            // 0..31
  int bq = (threadIdx.x & 7) << 3;      // 0..56 step 8
  #pragma unroll
  for (int q = 0; q < 2; ++q) {
    int kl = q * 32 + kr;
    *(uint4*)(xT + (size_t)(kb + kl) * B_ + bb + bq) = *(const uint4*)&tile[kl][bq];
  }
}

// ---- softmax over r (axis 0) per column c; 1 wave per column, 3 rows/lane
__global__ void k_softmax(const float* __restrict__ bij, float* __restrict__ cij) {
  int c = blockIdx.x; int l = threadIdx.x;
  float v0 = bij[l * C_ + c], v1 = bij[(l + 64) * C_ + c], v2 = bij[(l + 128) * C_ + c];
  float m = fmaxf(v0, fmaxf(v1, v2));
  for (int off = 32; off > 0; off >>= 1) m = fmaxf(m, __shfl_down(m, off));
  m = __shfl(m, 0);
  float e0 = expf(v0 - m), e1 = expf(v1 - m), e2 = expf(v2 - m);
  float s = e0 + e1 + e2;
  for (int off = 32; off > 0; off >>= 1) s += __shfl_down(s, off);
  s = __shfl(s, 0);
  float inv = 1.0f / s;
  cij[l * C_ + c] = e0 * inv;
  cij[(l + 64) * C_ + c] = e1 * inv;
  cij[(l + 128) * C_ + c] = e2 * inv;
}

// ---- WsT = WtT * c[k/20, n/16]   (8 bf16 per thread)
__global__ void k_scale_w(const u16* __restrict__ WtT, const float* __restrict__ cij,
                          u16* __restrict__ WsT) {
  int t = blockIdx.x * 256 + threadIdx.x;      // over N_*K1/8 = 737,280
  int n = t / 480;                             // K1/8 = 480 groups per row
  int kg = t - n * 480;
  int k0 = kg << 3;
  int ccol = n >> 4;
  uint4 w = ((const uint4*)WtT)[t];
  union { uint4 q; u16 h[8]; } u; u.q = w;
  #pragma unroll
  for (int e = 0; e < 8; ++e) {
    int r = (k0 + e) / I_;
    float sc = cij[r * C_ + ccol];
    u.h[e] = f2bf(bf2f(u.h[e]) * sc);
  }
  ((uint4*)WsT)[t] = u.q;
}

// ---- TN GEMM: C = A[M,K](rm,bf16) x Bt[N,K](rm,bf16), fp32 out (ld = N_).
// 128x128 tile, BK=32, 4 waves of 64x64 (4x4 MFMA 16x16x32 bf16).
// blockIdx.z selects a K-chunk; partial stored at C + z*zStride (no atomics).
__global__ __launch_bounds__(256) void gemm_tn(
    const u16* __restrict__ A, const u16* __restrict__ Bt,
    float* __restrict__ Cr, int K, int kChunk, int kIters, int zStride) {
  __shared__ u16 As[128 * 32];
  __shared__ u16 Bs[128 * 32];
  int tid = threadIdx.x;
  long m0 = (long)blockIdx.x * 128, n0 = (long)blockIdx.y * 128;
  int k0 = blockIdx.z * kChunk;
  const u16* Ab = A + m0 * K + k0;
  const u16* Bb = Bt + n0 * K + k0;
  int srow = tid >> 2;              // 0..63 (+64 for second load)
  int scol = (tid & 3) << 3;        // 0,8,16,24 elements
  int w = tid >> 6, lane = tid & 63;
  int wm = (w >> 1) << 6, wn = (w & 1) << 6;
  int quad = lane >> 4, lrow = lane & 15;
  floatx4 acc[4][4];
  #pragma unroll
  for (int a = 0; a < 4; ++a)
    #pragma unroll
    for (int b = 0; b < 4; ++b) acc[a][b] = (floatx4){0.f, 0.f, 0.f, 0.f};

  for (int kt = 0; kt < kIters; ++kt) {
    int kk = kt << 5;
    uint4 a0 = *(const uint4*)(Ab + (long)srow * K + kk + scol);
    uint4 a1 = *(const uint4*)(Ab + (long)(srow + 64) * K + kk + scol);
    uint4 b0 = *(const uint4*)(Bb + (long)srow * K + kk + scol);
    uint4 b1 = *(const uint4*)(Bb + (long)(srow + 64) * K + kk + scol);
    __syncthreads();                 // previous iter's frag reads done
    ((uint4*)As)[tid] = a0;
    ((uint4*)As)[tid + 256] = a1;
    ((uint4*)Bs)[tid] = b0;
    ((uint4*)Bs)[tid + 256] = b1;
    __syncthreads();
    short8 af[4], bfr[4];
    #pragma unroll
    for (int ms = 0; ms < 4; ++ms)
      af[ms] = *(const short8*)&As[(wm + ms * 16 + lrow) * 32 + (quad << 3)];
    #pragma unroll
    for (int ns = 0; ns < 4; ++ns)
      bfr[ns] = *(const short8*)&Bs[(wn + ns * 16 + lrow) * 32 + (quad << 3)];
    #pragma unroll
    for (int ms = 0; ms < 4; ++ms)
      #pragma unroll
      for (int ns = 0; ns < 4; ++ns)
        acc[ms][ns] = __builtin_amdgcn_mfma_f32_16x16x32_bf16(
            af[ms], bfr[ns], acc[ms][ns], 0, 0, 0);
  }
  size_t zb = (size_t)blockIdx.z * (size_t)zStride;
  #pragma unroll
  for (int ms = 0; ms < 4; ++ms)
    #pragma unroll
    for (int ns = 0; ns < 4; ++ns) {
      int row = (int)m0 + wm + ms * 16 + (quad << 2);
      int col = (int)n0 + wn + ns * 16 + lrow;
      #pragma unroll
      for (int r = 0; r < 4; ++r)
        Cr[zb + (size_t)(row + r) * N_ + col] = acc[ms][ns][r];
    }
}

// ---- sum split-K partials: s[t] = sum_z P[z][t]
__global__ void k_reduce_s(const float* __restrict__ P, float* __restrict__ s) {
  int t = blockIdx.x * 256 + threadIdx.x;      // over 393,216
  float acc = 0.f;
  #pragma unroll
  for (int z = 0; z < 12; ++z) acc += P[(size_t)z * 393216 + t];
  s[t] = acc;
}

// ---- squash over O=16; out (fp32, last iter) and vT bf16 (iters 0,1)
__global__ void k_squash(const float* __restrict__ s, float* __restrict__ out,
                         u16* __restrict__ vT, int last) {
  int p = blockIdx.x * 256 + threadIdx.x;      // over B_*C_ = 24,576
  int c = p >> 8, b = p & 255;                 // b fastest -> vT writes coalesce
  union { float4 q[4]; float f[16]; } sv;
  const float4* sp = (const float4*)(s + (size_t)b * N_ + c * O_);
  sv.q[0] = sp[0]; sv.q[1] = sp[1]; sv.q[2] = sp[2]; sv.q[3] = sp[3];
  float nsq = 0.f;
  #pragma unroll
  for (int o = 0; o < 16; ++o) nsq += sv.f[o] * sv.f[o];
  float factor = nsq / ((1.0f + nsq) * sqrtf(nsq));
  #pragma unroll
  for (int o = 0; o < 16; ++o) sv.f[o] *= factor;
  if (last) {
    float4* op = (float4*)(out + (size_t)b * N_ + c * O_);
    op[0] = sv.q[0]; op[1] = sv.q[1]; op[2] = sv.q[2]; op[3] = sv.q[3];
  } else {
    #pragma unroll
    for (int o = 0; o < 16; ++o) vT[(size_t)(c * O_ + o) * B_ + b] = f2bf(sv.f[o]);
  }
}

// ---- agreement: bij[r,c] += (1/256) * sum_{i,o} W * Z ; one wave per (r,c)
__global__ void k_agree(const float* __restrict__ Z, const float* __restrict__ W,
                        float* __restrict__ bij) {
  int wid = (blockIdx.x * 256 + threadIdx.x) >> 6;   // 0..18431
  int lane = threadIdx.x & 63;
  int r = wid / C_, c = wid - r * C_;
  float partial = 0.f;
  #pragma unroll
  for (int j = 0; j < 5; ++j) {
    int e = lane + (j << 6);                         // 0..319 ; e = i*16+o
    int i = e >> 4, o = e & 15;
    float zv = Z[(size_t)(r * I_ + i) * N_ + c * O_ + o];
    float wv = W[(((size_t)(r * C_ + c) * O_ + o) * I_) + i];
    partial += zv * wv;
  }
  for (int off = 32; off > 0; off >>= 1) partial += __shfl_down(partial, off);
  if (lane == 0) bij[r * C_ + c] += partial * (1.0f / 256.0f);
}

extern "C" void kernel_launch(void* const* d_in, const int* in_sizes, int n_in,
                              void* d_out, int out_size, void* d_ws, size_t ws_size,
                              hipStream_t stream) {
  const float* X = (const float*)d_in[0];   // fp32 [256,192,20] == [256,3840]
  const float* W = (const float*)d_in[1];   // fp32 [192,96,16,20]
  float* out = (float*)d_out;               // fp32 [256,96,16]
  char* ws = (char*)d_ws;
  // workspace layout (all 256B aligned), total ~53.6 MB
  u16*  WtT = (u16*)(ws);               // [1536][3840] bf16  11,796,480 B
  u16*  WsT = (u16*)(ws + 11796480);    // [1536][3840] bf16  11,796,480 B
  u16*  Xk  = (u16*)(ws + 23592960);    // [256][3840]  bf16   1,966,080 B
  u16*  xT  = (u16*)(ws + 25559040);    // [3840][256]  bf16   1,966,080 B
  float* s  = (float*)(ws + 27525120);  // [256][1536]  f32    1,572,864 B
  u16*  vT  = (u16*)(ws + 29097984);    // [1536][256]  bf16     786,432 B
  float* Zb = (float*)(ws + 29884416);  // [3840][1536] f32 (and GEMM1 partials) 23,592,960 B
  float* bij = (float*)(ws + 53477376); // [192][96] f32          73,728 B
  float* cij = (float*)(ws + 53551104); // [192][96] f32          73,728 B

  hipMemsetAsync(bij, 0, 73728, stream);
  k_prep_w<<<23040, 256, 0, stream>>>(W, WtT);
  k_cast_x<<<960, 256, 0, stream>>>(X, Xk);
  k_trans_x<<<dim3(60, 4), 256, 0, stream>>>(X, xT);

  for (int it = 0; it < 3; ++it) {
    k_softmax<<<96, 64, 0, stream>>>(bij, cij);
    k_scale_w<<<2880, 256, 0, stream>>>(WtT, cij, WsT);
    // s partials: M=256,N=1536,K=3840 split 12 ways (chunk 320 = 10 k-iters)
    gemm_tn<<<dim3(2, 12, 12), 256, 0, stream>>>(Xk, WsT, Zb, K1, 320, 10, 393216);
    k_reduce_s<<<1536, 256, 0, stream>>>(Zb, s);
    k_squash<<<96, 256, 0, stream>>>(s, out, vT, it == 2);
    if (it < 2) {
      // Z = xT @ vT^T : M=3840,N=1536,K=256 (8 k-iters, no split)
      gemm_tn<<<dim3(30, 12, 1), 256, 0, stream>>>(xT, vT, Zb, 256, 256, 8, 0);
      k_agree<<<4608, 256, 0, stream>>>(Zb, W, bij);
    }
  }
}

// Round 3
// 244.987 us; speedup vs baseline: 1.0325x; 1.0325x over previous
//
#include <hip/hip_runtime.h>

// DigitCaps dynamic routing, B=256 R=192 C=96 O=16 I=20. fp32 in/out.
// u_hat ([256,192,96,16] = 302 MB) never materialized:
//   s = Xk[256,3840](bf16) @ WsT[1536,3840](bf16 k-major), WsT = c[r,c]*W
//   Z-tile (in regs only) = xT[3840,256] @ vT[1536,256]^T; agreement reduced
//   in GEMM2 epilogue: bij[r,c] += (1/256) sum WtT[n,k]*Z[k,n]

#define R_ 192
#define C_ 96
#define O_ 16
#define I_ 20
#define B_ 256
#define K1 3840   // R*I
#define N_ 1536   // C*O
#define ZSPLIT 20
#define STILE 393216  // B_*N_

typedef unsigned short u16;
typedef __attribute__((ext_vector_type(8))) short short8;
typedef __attribute__((ext_vector_type(4))) float floatx4;

__device__ inline float bf2f(u16 h) {
  union { unsigned int u; float f; } x; x.u = ((unsigned int)h) << 16; return x.f;
}
__device__ inline u16 f2bf(float f) {
  union { float f; unsigned int u; } x; x.f = f;
  unsigned int r = x.u + 0x7FFFu + ((x.u >> 16) & 1u);
  return (u16)(r >> 16);
}

// ---- prep: W[r,c,o,i] fp32 -> WtT[(c*16+o)*3840+r*20+i] bf16, and
//      WsT = WtT * (1/192)  (iteration-0 coupling: softmax(0) = 1/192)
__global__ void k_prep_w(const float* __restrict__ W, u16* __restrict__ WtT,
                         u16* __restrict__ WsT) {
  int t = blockIdx.x * 256 + threadIdx.x;      // over N_*K1 = 5,898,240
  int n = t / K1, k = t - n * K1;
  int c = n >> 4, o = n & 15;
  int r = k / I_, i = k - r * I_;
  float w = W[(((r * C_ + c) * O_ + o) * I_) + i];
  WtT[t] = f2bf(w);
  WsT[t] = f2bf(w * (1.0f / 192.0f));
}

// ---- X fp32 [256,3840] -> Xk bf16 (same layout) + xT bf16 [3840,256]
__global__ void k_prep_x(const float* __restrict__ X, u16* __restrict__ Xk,
                         u16* __restrict__ xT) {
  __shared__ u16 tile[64][72];
  int kb = blockIdx.x << 6, bb = blockIdx.y << 6;
  int brow = threadIdx.x >> 4;          // 0..15
  int kq = (threadIdx.x & 15) << 2;     // 0..60 step 4
  #pragma unroll
  for (int p = 0; p < 4; ++p) {
    int bl = p * 16 + brow;
    float4 v = *(const float4*)(X + (size_t)(bb + bl) * K1 + kb + kq);
    ushort4 h;
    h.x = f2bf(v.x); h.y = f2bf(v.y); h.z = f2bf(v.z); h.w = f2bf(v.w);
    *(ushort4*)(Xk + (size_t)(bb + bl) * K1 + kb + kq) = h;
    tile[kq + 0][bl] = h.x;
    tile[kq + 1][bl] = h.y;
    tile[kq + 2][bl] = h.z;
    tile[kq + 3][bl] = h.w;
  }
  __syncthreads();
  int kr = threadIdx.x >> 3;            // 0..31
  int bq = (threadIdx.x & 7) << 3;      // 0..56 step 8
  #pragma unroll
  for (int q = 0; q < 2; ++q) {
    int kl = q * 32 + kr;
    *(uint4*)(xT + (size_t)(kb + kl) * B_ + bb + bq) = *(const uint4*)&tile[kl][bq];
  }
}

// ---- fused softmax + scale: one block per n-row (1536 blocks).
// Recomputes softmax over r for c=n>>4 from bij, then WsT[n,:] = WtT[n,:]*c[r,c].
__global__ void k_scale(const u16* __restrict__ WtT, const float* __restrict__ bij,
                        u16* __restrict__ WsT) {
  __shared__ float sm[192];
  __shared__ float wred[4];
  int n = blockIdx.x, t = threadIdx.x;
  int c = n >> 4;
  float v = (t < R_) ? bij[t * C_ + c] : -1e30f;
  float m = v;
  #pragma unroll
  for (int off = 32; off > 0; off >>= 1) m = fmaxf(m, __shfl_xor(m, off));
  if ((t & 63) == 0) wred[t >> 6] = m;
  __syncthreads();
  m = fmaxf(fmaxf(wred[0], wred[1]), fmaxf(wred[2], wred[3]));
  float e = (t < R_) ? expf(v - m) : 0.0f;
  float ssum = e;
  #pragma unroll
  for (int off = 32; off > 0; off >>= 1) ssum += __shfl_xor(ssum, off);
  __syncthreads();
  if ((t & 63) == 0) wred[t >> 6] = ssum;
  __syncthreads();
  ssum = wred[0] + wred[1] + wred[2] + wred[3];
  if (t < R_) sm[t] = e / ssum;
  __syncthreads();
  const uint4* src = (const uint4*)WtT + (size_t)n * 480;
  uint4* dst = (uint4*)WsT + (size_t)n * 480;
  for (int idx = t; idx < 480; idx += 256) {
    union { uint4 q; u16 h[8]; } u; u.q = src[idx];
    int k0 = idx << 3;
    #pragma unroll
    for (int eidx = 0; eidx < 8; ++eidx) {
      int r = (k0 + eidx) / I_;
      u.h[eidx] = f2bf(bf2f(u.h[eidx]) * sm[r]);
    }
    dst[idx] = u.q;
  }
}

// ---- GEMM1: P[z] = Xk[256,3840] x WsT[1536,3840]^T (k-chunk z), fp32 partials.
// 128x128 tile, BK=32, 4 waves of 64x64 (4x4 MFMA 16x16x32 bf16).
__global__ __launch_bounds__(256) void gemm_tn(
    const u16* __restrict__ A, const u16* __restrict__ Bt,
    float* __restrict__ Cr, int K, int kChunk, int kIters, int zStride) {
  __shared__ u16 As[128 * 32];
  __shared__ u16 Bs[128 * 32];
  int tid = threadIdx.x;
  long m0 = (long)blockIdx.x * 128, n0 = (long)blockIdx.y * 128;
  int k0 = blockIdx.z * kChunk;
  const u16* Ab = A + m0 * K + k0;
  const u16* Bb = Bt + n0 * K + k0;
  int srow = tid >> 2;
  int scol = (tid & 3) << 3;
  int w = tid >> 6, lane = tid & 63;
  int wm = (w >> 1) << 6, wn = (w & 1) << 6;
  int quad = lane >> 4, lrow = lane & 15;
  floatx4 acc[4][4];
  #pragma unroll
  for (int a = 0; a < 4; ++a)
    #pragma unroll
    for (int b = 0; b < 4; ++b) acc[a][b] = (floatx4){0.f, 0.f, 0.f, 0.f};

  for (int kt = 0; kt < kIters; ++kt) {
    int kk = kt << 5;
    uint4 a0 = *(const uint4*)(Ab + (long)srow * K + kk + scol);
    uint4 a1 = *(const uint4*)(Ab + (long)(srow + 64) * K + kk + scol);
    uint4 b0 = *(const uint4*)(Bb + (long)srow * K + kk + scol);
    uint4 b1 = *(const uint4*)(Bb + (long)(srow + 64) * K + kk + scol);
    __syncthreads();
    ((uint4*)As)[tid] = a0;
    ((uint4*)As)[tid + 256] = a1;
    ((uint4*)Bs)[tid] = b0;
    ((uint4*)Bs)[tid + 256] = b1;
    __syncthreads();
    short8 af[4], bfr[4];
    #pragma unroll
    for (int ms = 0; ms < 4; ++ms)
      af[ms] = *(const short8*)&As[(wm + ms * 16 + lrow) * 32 + (quad << 3)];
    #pragma unroll
    for (int ns = 0; ns < 4; ++ns)
      bfr[ns] = *(const short8*)&Bs[(wn + ns * 16 + lrow) * 32 + (quad << 3)];
    #pragma unroll
    for (int ms = 0; ms < 4; ++ms)
      #pragma unroll
      for (int ns = 0; ns < 4; ++ns)
        acc[ms][ns] = __builtin_amdgcn_mfma_f32_16x16x32_bf16(
            af[ms], bfr[ns], acc[ms][ns], 0, 0, 0);
  }
  size_t zb = (size_t)blockIdx.z * (size_t)zStride;
  #pragma unroll
  for (int ms = 0; ms < 4; ++ms)
    #pragma unroll
    for (int ns = 0; ns < 4; ++ns) {
      int row = (int)m0 + wm + ms * 16 + (quad << 2);
      int col = (int)n0 + wn + ns * 16 + lrow;
      #pragma unroll
      for (int r = 0; r < 4; ++r)
        Cr[zb + (size_t)(row + r) * N_ + col] = acc[ms][ns][r];
    }
}

// ---- GEMM2 + agreement fused: Z-tile stays in registers; epilogue contracts
// against WtT and atomically accumulates bij[r,c] += sum/256. No C write.
__global__ __launch_bounds__(256) void gemm2_agree(
    const u16* __restrict__ A, const u16* __restrict__ Bt,
    const u16* __restrict__ WtT, float* __restrict__ bij) {
  const int K = 256;
  __shared__ u16 As[128 * 32];
  __shared__ u16 Bs[128 * 32];
  int tid = threadIdx.x;
  long m0 = (long)blockIdx.x * 128, n0 = (long)blockIdx.y * 128;
  const u16* Ab = A + m0 * K;
  const u16* Bb = Bt + n0 * K;
  int srow = tid >> 2;
  int scol = (tid & 3) << 3;
  int w = tid >> 6, lane = tid & 63;
  int wm = (w >> 1) << 6, wn = (w & 1) << 6;
  int quad = lane >> 4, lrow = lane & 15;
  floatx4 acc[4][4];
  #pragma unroll
  for (int a = 0; a < 4; ++a)
    #pragma unroll
    for (int b = 0; b < 4; ++b) acc[a][b] = (floatx4){0.f, 0.f, 0.f, 0.f};

  for (int kt = 0; kt < 8; ++kt) {
    int kk = kt << 5;
    uint4 a0 = *(const uint4*)(Ab + (long)srow * K + kk + scol);
    uint4 a1 = *(const uint4*)(Ab + (long)(srow + 64) * K + kk + scol);
    uint4 b0 = *(const uint4*)(Bb + (long)srow * K + kk + scol);
    uint4 b1 = *(const uint4*)(Bb + (long)(srow + 64) * K + kk + scol);
    __syncthreads();
    ((uint4*)As)[tid] = a0;
    ((uint4*)As)[tid + 256] = a1;
    ((uint4*)Bs)[tid] = b0;
    ((uint4*)Bs)[tid + 256] = b1;
    __syncthreads();
    short8 af[4], bfr[4];
    #pragma unroll
    for (int ms = 0; ms < 4; ++ms)
      af[ms] = *(const short8*)&As[(wm + ms * 16 + lrow) * 32 + (quad << 3)];
    #pragma unroll
    for (int ns = 0; ns < 4; ++ns)
      bfr[ns] = *(const short8*)&Bs[(wn + ns * 16 + lrow) * 32 + (quad << 3)];
    #pragma unroll
    for (int ms = 0; ms < 4; ++ms)
      #pragma unroll
      for (int ns = 0; ns < 4; ++ns)
        acc[ms][ns] = __builtin_amdgcn_mfma_f32_16x16x32_bf16(
            af[ms], bfr[ns], acc[ms][ns], 0, 0, 0);
  }
  // epilogue: per fragment, cols = one capsule c; 16 rows span <=2 routes r.
  #pragma unroll
  for (int ms = 0; ms < 4; ++ms) {
    int rowbase = (int)m0 + wm + ms * 16;          // wave-uniform
    int r_lo = rowbase / I_;
    int r_hi = (rowbase + 15) / I_;
    int bnd = (r_lo + 1) * I_;
    int rowl = rowbase + (quad << 2);
    #pragma unroll
    for (int ns = 0; ns < 4; ++ns) {
      int col = (int)n0 + wn + ns * 16 + lrow;
      uint2 wv = *(const uint2*)&WtT[(size_t)col * K1 + rowl];
      u16 h[4];
      h[0] = (u16)(wv.x & 0xffff); h[1] = (u16)(wv.x >> 16);
      h[2] = (u16)(wv.y & 0xffff); h[3] = (u16)(wv.y >> 16);
      float p0 = 0.f, p1 = 0.f;
      #pragma unroll
      for (int e = 0; e < 4; ++e) {
        float pr = acc[ms][ns][e] * bf2f(h[e]);
        if (rowl + e < bnd) p0 += pr; else p1 += pr;
      }
      #pragma unroll
      for (int off = 32; off > 0; off >>= 1) {
        p0 += __shfl_xor(p0, off);
        p1 += __shfl_xor(p1, off);
      }
      if (lane == 0) {
        int c = col >> 4;                          // lrow==0 -> tile-uniform
        atomicAdd(&bij[r_lo * C_ + c], p0 * (1.0f / 256.0f));
        atomicAdd(&bij[r_hi * C_ + c], p1 * (1.0f / 256.0f));
      }
    }
  }
}

// ---- fused split-K reduce + squash; vT (iters 0,1) or out (last)
__global__ void k_redsq(const float* __restrict__ P, float* __restrict__ out,
                        u16* __restrict__ vT, int last) {
  int p = blockIdx.x * 256 + threadIdx.x;      // over B_*C_ = 24,576
  int b = p & 255, c = p >> 8;
  float f[16];
  #pragma unroll
  for (int o = 0; o < 16; ++o) f[o] = 0.f;
  for (int z = 0; z < ZSPLIT; ++z) {
    const float4* sp = (const float4*)(P + (size_t)z * STILE + (size_t)b * N_ + c * O_);
    #pragma unroll
    for (int j = 0; j < 4; ++j) {
      float4 v = sp[j];
      f[j * 4 + 0] += v.x; f[j * 4 + 1] += v.y; f[j * 4 + 2] += v.z; f[j * 4 + 3] += v.w;
    }
  }
  float nsq = 0.f;
  #pragma unroll
  for (int o = 0; o < 16; ++o) nsq += f[o] * f[o];
  float factor = nsq / ((1.0f + nsq) * sqrtf(nsq));
  #pragma unroll
  for (int o = 0; o < 16; ++o) f[o] *= factor;
  if (last) {
    float4* op = (float4*)(out + (size_t)b * N_ + c * O_);
    #pragma unroll
    for (int j = 0; j < 4; ++j)
      op[j] = (float4){f[j * 4], f[j * 4 + 1], f[j * 4 + 2], f[j * 4 + 3]};
  } else {
    #pragma unroll
    for (int o = 0; o < 16; ++o) vT[(size_t)(c * O_ + o) * B_ + b] = f2bf(f[o]);
  }
}

extern "C" void kernel_launch(void* const* d_in, const int* in_sizes, int n_in,
                              void* d_out, int out_size, void* d_ws, size_t ws_size,
                              hipStream_t stream) {
  const float* X = (const float*)d_in[0];   // fp32 [256,192,20]
  const float* W = (const float*)d_in[1];   // fp32 [192,96,16,20]
  float* out = (float*)d_out;               // fp32 [256,96,16]
  char* ws = (char*)d_ws;
  u16*  WtT = (u16*)(ws);                   // 11,796,480 B
  u16*  WsT = (u16*)(ws + 11796480);        // 11,796,480 B
  u16*  Xk  = (u16*)(ws + 23592960);        //  1,966,080 B
  u16*  xT  = (u16*)(ws + 25559040);        //  1,966,080 B
  u16*  vT  = (u16*)(ws + 27525120);        //    786,432 B
  float* Pb = (float*)(ws + 28311552);      // 20 x 1,572,864 B = 31,457,280 B
  float* bij = (float*)(ws + 59768832);     //     73,728 B

  hipMemsetAsync(bij, 0, 73728, stream);
  k_prep_w<<<23040, 256, 0, stream>>>(W, WtT, WsT);
  k_prep_x<<<dim3(60, 4), 256, 0, stream>>>(X, Xk, xT);

  for (int it = 0; it < 3; ++it) {
    if (it > 0)
      k_scale<<<1536, 256, 0, stream>>>(WtT, bij, WsT);
    // s partials: M=256,N=1536,K=3840 split 20 ways (chunk 192 = 6 k-iters)
    gemm_tn<<<dim3(2, 12, ZSPLIT), 256, 0, stream>>>(Xk, WsT, Pb, K1, 192, 6, STILE);
    k_redsq<<<96, 256, 0, stream>>>(Pb, out, vT, it == 2);
    if (it < 2)
      gemm2_agree<<<dim3(30, 12), 256, 0, stream>>>(xT, vT, WtT, bij);
  }
}

// Round 4
// 186.476 us; speedup vs baseline: 1.3565x; 1.3138x over previous
//
#include <hip/hip_runtime.h>

// DigitCaps dynamic routing, B=256 R=192 C=96 O=16 I=20. fp32 in/out.
// u_hat ([256,192,96,16] = 302 MB) never materialized:
//   s = Xk[256,3840](bf16) @ WsT[1536,3840](bf16 k-major), WsT = c[r,c]*W
//   GEMM1 split-K partials stored TRANSPOSED bf16: P^T[z][n][b]  (coalesced
//   reduce + coalesced vT write downstream)
//   Z-tile (in regs only) = xT[3840,256] @ vT[1536,256]^T; agreement reduced
//   in GEMM2 epilogue: bij[r,c] += (1/256) sum WtT[n,k]*Z[k,n]

#define R_ 192
#define C_ 96
#define O_ 16
#define I_ 20
#define B_ 256
#define K1 3840   // R*I
#define N_ 1536   // C*O
#define ZSPLIT 20
#define STILE 393216  // N_*B_ elements per z-slice

typedef unsigned short u16;
typedef __attribute__((ext_vector_type(8))) short short8;
typedef __attribute__((ext_vector_type(4))) float floatx4;

__device__ inline float bf2f(u16 h) {
  union { unsigned int u; float f; } x; x.u = ((unsigned int)h) << 16; return x.f;
}
__device__ inline u16 f2bf(float f) {
  union { float f; unsigned int u; } x; x.f = f;
  unsigned int r = x.u + 0x7FFFu + ((x.u >> 16) & 1u);
  return (u16)(r >> 16);
}
__device__ inline unsigned int pack2(float a, float b) {
  return (unsigned int)f2bf(a) | ((unsigned int)f2bf(b) << 16);
}

// ---- prep: W[r,c,o,i] fp32 -> WtT[(c*16+o)*3840+r*20+i] bf16, and
//      WsT = WtT * (1/192)  (iteration-0 coupling: softmax(0) = 1/192)
__global__ void k_prep_w(const float* __restrict__ W, u16* __restrict__ WtT,
                         u16* __restrict__ WsT) {
  int t = blockIdx.x * 256 + threadIdx.x;      // over N_*K1 = 5,898,240
  int n = t / K1, k = t - n * K1;
  int c = n >> 4, o = n & 15;
  int r = k / I_, i = k - r * I_;
  float w = W[(((r * C_ + c) * O_ + o) * I_) + i];
  WtT[t] = f2bf(w);
  WsT[t] = f2bf(w * (1.0f / 192.0f));
}

// ---- X fp32 [256,3840] -> Xk bf16 (same layout) + xT bf16 [3840,256]
__global__ void k_prep_x(const float* __restrict__ X, u16* __restrict__ Xk,
                         u16* __restrict__ xT) {
  __shared__ u16 tile[64][72];
  int kb = blockIdx.x << 6, bb = blockIdx.y << 6;
  int brow = threadIdx.x >> 4;          // 0..15
  int kq = (threadIdx.x & 15) << 2;     // 0..60 step 4
  #pragma unroll
  for (int p = 0; p < 4; ++p) {
    int bl = p * 16 + brow;
    float4 v = *(const float4*)(X + (size_t)(bb + bl) * K1 + kb + kq);
    ushort4 h;
    h.x = f2bf(v.x); h.y = f2bf(v.y); h.z = f2bf(v.z); h.w = f2bf(v.w);
    *(ushort4*)(Xk + (size_t)(bb + bl) * K1 + kb + kq) = h;
    tile[kq + 0][bl] = h.x;
    tile[kq + 1][bl] = h.y;
    tile[kq + 2][bl] = h.z;
    tile[kq + 3][bl] = h.w;
  }
  __syncthreads();
  int kr = threadIdx.x >> 3;            // 0..31
  int bq = (threadIdx.x & 7) << 3;      // 0..56 step 8
  #pragma unroll
  for (int q = 0; q < 2; ++q) {
    int kl = q * 32 + kr;
    *(uint4*)(xT + (size_t)(kb + kl) * B_ + bb + bq) = *(const uint4*)&tile[kl][bq];
  }
}

// ---- fused softmax + scale: one block per n-row (1536 blocks).
__global__ void k_scale(const u16* __restrict__ WtT, const float* __restrict__ bij,
                        u16* __restrict__ WsT) {
  __shared__ float sm[192];
  __shared__ float wred[4];
  int n = blockIdx.x, t = threadIdx.x;
  int c = n >> 4;
  float v = (t < R_) ? bij[t * C_ + c] : -1e30f;
  float m = v;
  #pragma unroll
  for (int off = 32; off > 0; off >>= 1) m = fmaxf(m, __shfl_xor(m, off));
  if ((t & 63) == 0) wred[t >> 6] = m;
  __syncthreads();
  m = fmaxf(fmaxf(wred[0], wred[1]), fmaxf(wred[2], wred[3]));
  float e = (t < R_) ? expf(v - m) : 0.0f;
  float ssum = e;
  #pragma unroll
  for (int off = 32; off > 0; off >>= 1) ssum += __shfl_xor(ssum, off);
  __syncthreads();
  if ((t & 63) == 0) wred[t >> 6] = ssum;
  __syncthreads();
  ssum = wred[0] + wred[1] + wred[2] + wred[3];
  if (t < R_) sm[t] = e / ssum;
  __syncthreads();
  const uint4* src = (const uint4*)WtT + (size_t)n * 480;
  uint4* dst = (uint4*)WsT + (size_t)n * 480;
  for (int idx = t; idx < 480; idx += 256) {
    union { uint4 q; u16 h[8]; } u; u.q = src[idx];
    int k0 = idx << 3;
    #pragma unroll
    for (int eidx = 0; eidx < 8; ++eidx) {
      int r = (k0 + eidx) / I_;
      u.h[eidx] = f2bf(bf2f(u.h[eidx]) * sm[r]);
    }
    dst[idx] = u.q;
  }
}

// ---- GEMM1: P^T[z][n][b] (bf16) = (Xk[256,3840] x WsT[1536,3840]^T) chunk z.
// 128x128 tile, BK=32, 4 waves of 64x64 (4x4 MFMA 16x16x32 bf16).
__global__ __launch_bounds__(256) void gemm1(
    const u16* __restrict__ A, const u16* __restrict__ Bt,
    u16* __restrict__ P, int kChunk, int kIters) {
  const int K = K1;
  __shared__ u16 As[128 * 32];
  __shared__ u16 Bs[128 * 32];
  int tid = threadIdx.x;
  long m0 = (long)blockIdx.x * 128, n0 = (long)blockIdx.y * 128;
  int k0 = blockIdx.z * kChunk;
  const u16* Ab = A + m0 * K + k0;
  const u16* Bb = Bt + n0 * K + k0;
  int srow = tid >> 2;
  int scol = (tid & 3) << 3;
  int w = tid >> 6, lane = tid & 63;
  int wm = (w >> 1) << 6, wn = (w & 1) << 6;
  int quad = lane >> 4, lrow = lane & 15;
  floatx4 acc[4][4];
  #pragma unroll
  for (int a = 0; a < 4; ++a)
    #pragma unroll
    for (int b = 0; b < 4; ++b) acc[a][b] = (floatx4){0.f, 0.f, 0.f, 0.f};

  for (int kt = 0; kt < kIters; ++kt) {
    int kk = kt << 5;
    uint4 a0 = *(const uint4*)(Ab + (long)srow * K + kk + scol);
    uint4 a1 = *(const uint4*)(Ab + (long)(srow + 64) * K + kk + scol);
    uint4 b0 = *(const uint4*)(Bb + (long)srow * K + kk + scol);
    uint4 b1 = *(const uint4*)(Bb + (long)(srow + 64) * K + kk + scol);
    __syncthreads();
    ((uint4*)As)[tid] = a0;
    ((uint4*)As)[tid + 256] = a1;
    ((uint4*)Bs)[tid] = b0;
    ((uint4*)Bs)[tid + 256] = b1;
    __syncthreads();
    short8 af[4], bfr[4];
    #pragma unroll
    for (int ms = 0; ms < 4; ++ms)
      af[ms] = *(const short8*)&As[(wm + ms * 16 + lrow) * 32 + (quad << 3)];
    #pragma unroll
    for (int ns = 0; ns < 4; ++ns)
      bfr[ns] = *(const short8*)&Bs[(wn + ns * 16 + lrow) * 32 + (quad << 3)];
    #pragma unroll
    for (int ms = 0; ms < 4; ++ms)
      #pragma unroll
      for (int ns = 0; ns < 4; ++ns)
        acc[ms][ns] = __builtin_amdgcn_mfma_f32_16x16x32_bf16(
            af[ms], bfr[ns], acc[ms][ns], 0, 0, 0);
  }
  // transposed bf16 store: P[z][n*256 + b]; lane holds 4 consecutive b (quad rows)
  size_t zb = (size_t)blockIdx.z * (size_t)STILE;
  #pragma unroll
  for (int ms = 0; ms < 4; ++ms)
    #pragma unroll
    for (int ns = 0; ns < 4; ++ns) {
      int b = (int)m0 + wm + ms * 16 + (quad << 2);
      int n = (int)n0 + wn + ns * 16 + lrow;
      uint2 pk;
      pk.x = pack2(acc[ms][ns][0], acc[ms][ns][1]);
      pk.y = pack2(acc[ms][ns][2], acc[ms][ns][3]);
      *(uint2*)&P[zb + (size_t)n * B_ + b] = pk;
    }
}

// ---- GEMM2 + agreement fused: Z-tile stays in registers; epilogue contracts
// against WtT and atomically accumulates bij[r,c] += sum/256. No C write.
__global__ __launch_bounds__(256) void gemm2_agree(
    const u16* __restrict__ A, const u16* __restrict__ Bt,
    const u16* __restrict__ WtT, float* __restrict__ bij) {
  const int K = 256;
  __shared__ u16 As[128 * 32];
  __shared__ u16 Bs[128 * 32];
  int tid = threadIdx.x;
  long m0 = (long)blockIdx.x * 128, n0 = (long)blockIdx.y * 128;
  const u16* Ab = A + m0 * K;
  const u16* Bb = Bt + n0 * K;
  int srow = tid >> 2;
  int scol = (tid & 3) << 3;
  int w = tid >> 6, lane = tid & 63;
  int wm = (w >> 1) << 6, wn = (w & 1) << 6;
  int quad = lane >> 4, lrow = lane & 15;
  floatx4 acc[4][4];
  #pragma unroll
  for (int a = 0; a < 4; ++a)
    #pragma unroll
    for (int b = 0; b < 4; ++b) acc[a][b] = (floatx4){0.f, 0.f, 0.f, 0.f};

  for (int kt = 0; kt < 8; ++kt) {
    int kk = kt << 5;
    uint4 a0 = *(const uint4*)(Ab + (long)srow * K + kk + scol);
    uint4 a1 = *(const uint4*)(Ab + (long)(srow + 64) * K + kk + scol);
    uint4 b0 = *(const uint4*)(Bb + (long)srow * K + kk + scol);
    uint4 b1 = *(const uint4*)(Bb + (long)(srow + 64) * K + kk + scol);
    __syncthreads();
    ((uint4*)As)[tid] = a0;
    ((uint4*)As)[tid + 256] = a1;
    ((uint4*)Bs)[tid] = b0;
    ((uint4*)Bs)[tid + 256] = b1;
    __syncthreads();
    short8 af[4], bfr[4];
    #pragma unroll
    for (int ms = 0; ms < 4; ++ms)
      af[ms] = *(const short8*)&As[(wm + ms * 16 + lrow) * 32 + (quad << 3)];
    #pragma unroll
    for (int ns = 0; ns < 4; ++ns)
      bfr[ns] = *(const short8*)&Bs[(wn + ns * 16 + lrow) * 32 + (quad << 3)];
    #pragma unroll
    for (int ms = 0; ms < 4; ++ms)
      #pragma unroll
      for (int ns = 0; ns < 4; ++ns)
        acc[ms][ns] = __builtin_amdgcn_mfma_f32_16x16x32_bf16(
            af[ms], bfr[ns], acc[ms][ns], 0, 0, 0);
  }
  // epilogue: per fragment, cols = one capsule c; 16 rows span <=2 routes r.
  #pragma unroll
  for (int ms = 0; ms < 4; ++ms) {
    int rowbase = (int)m0 + wm + ms * 16;          // wave-uniform
    int r_lo = rowbase / I_;
    int r_hi = (rowbase + 15) / I_;
    int bnd = (r_lo + 1) * I_;
    int rowl = rowbase + (quad << 2);
    #pragma unroll
    for (int ns = 0; ns < 4; ++ns) {
      int col = (int)n0 + wn + ns * 16 + lrow;
      uint2 wv = *(const uint2*)&WtT[(size_t)col * K1 + rowl];
      u16 h[4];
      h[0] = (u16)(wv.x & 0xffff); h[1] = (u16)(wv.x >> 16);
      h[2] = (u16)(wv.y & 0xffff); h[3] = (u16)(wv.y >> 16);
      float p0 = 0.f, p1 = 0.f;
      #pragma unroll
      for (int e = 0; e < 4; ++e) {
        float pr = acc[ms][ns][e] * bf2f(h[e]);
        if (rowl + e < bnd) p0 += pr; else p1 += pr;
      }
      #pragma unroll
      for (int off = 32; off > 0; off >>= 1) {
        p0 += __shfl_xor(p0, off);
        p1 += __shfl_xor(p1, off);
      }
      if (lane == 0) {
        int c = col >> 4;
        atomicAdd(&bij[r_lo * C_ + c], p0 * (1.0f / 256.0f));
        atomicAdd(&bij[r_hi * C_ + c], p1 * (1.0f / 256.0f));
      }
    }
  }
}

// ---- fused split-K reduce + squash, reading P^T[z][n][b] bf16.
// grid (96 c, 2 b-halves), block 256 = 4 o-groups x 64 lanes; 2 b per lane.
__global__ void k_redsq(const u16* __restrict__ P, float* __restrict__ out,
                        u16* __restrict__ vT, int last) {
  __shared__ float nsq_l[4][128];
  int c = blockIdx.x, bh = blockIdx.y;
  int lane = threadIdx.x & 63, og = threadIdx.x >> 6;
  int bi = (lane << 1);                  // local b index (0..126 step 2)
  int b = (bh << 7) + bi;
  float acc[4][2];
  #pragma unroll
  for (int oo = 0; oo < 4; ++oo) { acc[oo][0] = 0.f; acc[oo][1] = 0.f; }
  for (int z = 0; z < ZSPLIT; ++z) {
    size_t base = (size_t)z * STILE + (size_t)((c << 4) + (og << 2)) * B_ + b;
    #pragma unroll
    for (int oo = 0; oo < 4; ++oo) {
      unsigned int u = *(const unsigned int*)&P[base + (size_t)oo * B_];
      acc[oo][0] += bf2f((u16)(u & 0xffff));
      acc[oo][1] += bf2f((u16)(u >> 16));
    }
  }
  float q0 = 0.f, q1 = 0.f;
  #pragma unroll
  for (int oo = 0; oo < 4; ++oo) {
    q0 += acc[oo][0] * acc[oo][0];
    q1 += acc[oo][1] * acc[oo][1];
  }
  nsq_l[og][bi] = q0;
  nsq_l[og][bi + 1] = q1;
  __syncthreads();
  float n0 = nsq_l[0][bi] + nsq_l[1][bi] + nsq_l[2][bi] + nsq_l[3][bi];
  float n1 = nsq_l[0][bi + 1] + nsq_l[1][bi + 1] + nsq_l[2][bi + 1] + nsq_l[3][bi + 1];
  float f0 = n0 / ((1.0f + n0) * sqrtf(n0));
  float f1 = n1 / ((1.0f + n1) * sqrtf(n1));
  #pragma unroll
  for (int oo = 0; oo < 4; ++oo) { acc[oo][0] *= f0; acc[oo][1] *= f1; }
  if (last) {
    float4 v0 = (float4){acc[0][0], acc[1][0], acc[2][0], acc[3][0]};
    float4 v1 = (float4){acc[0][1], acc[1][1], acc[2][1], acc[3][1]};
    *(float4*)(out + (size_t)b * N_ + (c << 4) + (og << 2)) = v0;
    *(float4*)(out + (size_t)(b + 1) * N_ + (c << 4) + (og << 2)) = v1;
  } else {
    #pragma unroll
    for (int oo = 0; oo < 4; ++oo)
      *(unsigned int*)&vT[(size_t)((c << 4) + (og << 2) + oo) * B_ + b] =
          pack2(acc[oo][0], acc[oo][1]);
  }
}

extern "C" void kernel_launch(void* const* d_in, const int* in_sizes, int n_in,
                              void* d_out, int out_size, void* d_ws, size_t ws_size,
                              hipStream_t stream) {
  const float* X = (const float*)d_in[0];   // fp32 [256,192,20]
  const float* W = (const float*)d_in[1];   // fp32 [192,96,16,20]
  float* out = (float*)d_out;               // fp32 [256,96,16]
  char* ws = (char*)d_ws;
  u16*  WtT = (u16*)(ws);                   // 11,796,480 B
  u16*  WsT = (u16*)(ws + 11796480);        // 11,796,480 B
  u16*  Xk  = (u16*)(ws + 23592960);        //  1,966,080 B
  u16*  xT  = (u16*)(ws + 25559040);        //  1,966,080 B
  u16*  vT  = (u16*)(ws + 27525120);        //    786,432 B
  u16*  Pb  = (u16*)(ws + 28311552);        // 20 x 786,432 B = 15,728,640 B
  float* bij = (float*)(ws + 44040192);     //     73,728 B

  hipMemsetAsync(bij, 0, 73728, stream);
  k_prep_w<<<23040, 256, 0, stream>>>(W, WtT, WsT);
  k_prep_x<<<dim3(60, 4), 256, 0, stream>>>(X, Xk, xT);

  for (int it = 0; it < 3; ++it) {
    if (it > 0)
      k_scale<<<1536, 256, 0, stream>>>(WtT, bij, WsT);
    // s partials: M=256,N=1536,K=3840 split 20 ways (chunk 192 = 6 k-iters)
    gemm1<<<dim3(2, 12, ZSPLIT), 256, 0, stream>>>(Xk, WsT, Pb, 192, 6);
    k_redsq<<<dim3(96, 2), 256, 0, stream>>>(Pb, out, vT, it == 2);
    if (it < 2)
      gemm2_agree<<<dim3(30, 12), 256, 0, stream>>>(xT, vT, WtT, bij);
  }
}

// Round 5
// 179.240 us; speedup vs baseline: 1.4112x; 1.0404x over previous
//
#include <hip/hip_runtime.h>

// DigitCaps dynamic routing, B=256 R=192 C=96 O=16 I=20. fp32 in/out.
// u_hat ([256,192,96,16] = 302 MB) never materialized. 9 dispatches total:
//   prep: W->WtT (bf16 k-major), X->Xk + xT, bij=0
//   gemm1 (x3): per-block softmax(bij) table; B-tile = WtT scaled at LDS
//     staging time; split-K partials stored transposed bf16 P^T[z][n][b]
//   redsq (x3): coalesced split-K reduce + squash -> vT (bf16) / out (fp32)
//   gemm2_agree (x2): Z-tile in regs; agreement contracted in epilogue with
//     WtT, atomicAdd into bij. K=256 split 2 ways (agreement is linear in Z).

#define R_ 192
#define C_ 96
#define O_ 16
#define I_ 20
#define B_ 256
#define K1 3840   // R*I
#define N_ 1536   // C*O
#define ZSPLIT 20
#define STILE 393216  // N_*B_ elements per z-slice

typedef unsigned short u16;
typedef __attribute__((ext_vector_type(8))) short short8;
typedef __attribute__((ext_vector_type(4))) float floatx4;

__device__ inline float bf2f(u16 h) {
  union { unsigned int u; float f; } x; x.u = ((unsigned int)h) << 16; return x.f;
}
__device__ inline u16 f2bf(float f) {
  union { float f; unsigned int u; } x; x.f = f;
  unsigned int r = x.u + 0x7FFFu + ((x.u >> 16) & 1u);
  return (u16)(r >> 16);
}
__device__ inline unsigned int pack2(float a, float b) {
  return (unsigned int)f2bf(a) | ((unsigned int)f2bf(b) << 16);
}

// ---- fused prep: W[r,c,o,i] fp32 -> WtT[(c*16+o)*3840+r*20+i] bf16 (23040
// blocks); X fp32 -> Xk bf16 + xT bf16 [3840,256] (240 blocks); bij=0 (72).
__global__ void k_prep(const float* __restrict__ W, const float* __restrict__ X,
                       u16* __restrict__ WtT, u16* __restrict__ Xk,
                       u16* __restrict__ xT, float* __restrict__ bij) {
  int bid = blockIdx.x;
  if (bid < 23040) {
    int t = bid * 256 + threadIdx.x;           // over N_*K1 = 5,898,240
    int n = t / K1, k = t - n * K1;
    int c = n >> 4, o = n & 15;
    int r = k / I_, i = k - r * I_;
    WtT[t] = f2bf(W[(((r * C_ + c) * O_ + o) * I_) + i]);
  } else if (bid < 23280) {
    __shared__ u16 tile[64][72];
    int idx = bid - 23040;
    int kb = (idx % 60) << 6, bb = (idx / 60) << 6;
    int brow = threadIdx.x >> 4;          // 0..15
    int kq = (threadIdx.x & 15) << 2;     // 0..60 step 4
    #pragma unroll
    for (int p = 0; p < 4; ++p) {
      int bl = p * 16 + brow;
      float4 v = *(const float4*)(X + (size_t)(bb + bl) * K1 + kb + kq);
      ushort4 h;
      h.x = f2bf(v.x); h.y = f2bf(v.y); h.z = f2bf(v.z); h.w = f2bf(v.w);
      *(ushort4*)(Xk + (size_t)(bb + bl) * K1 + kb + kq) = h;
      tile[kq + 0][bl] = h.x;
      tile[kq + 1][bl] = h.y;
      tile[kq + 2][bl] = h.z;
      tile[kq + 3][bl] = h.w;
    }
    __syncthreads();
    int kr = threadIdx.x >> 3;            // 0..31
    int bq = (threadIdx.x & 7) << 3;      // 0..56 step 8
    #pragma unroll
    for (int q = 0; q < 2; ++q) {
      int kl = q * 32 + kr;
      *(uint4*)(xT + (size_t)(kb + kl) * B_ + bb + bq) = *(const uint4*)&tile[kl][bq];
    }
  } else {
    int t = (bid - 23280) * 256 + threadIdx.x;  // over 18,432
    bij[t] = 0.0f;
  }
}

// scale 8 k-contiguous bf16 (global k = kg..kg+7) by softmax row(s)
__device__ inline uint4 scale_b8(uint4 raw, int kg, const float* smrow) {
  int r0 = kg / I_;
  int bnd = (r0 + 1) * I_ - kg;                // elements j<bnd use r0
  float s0 = smrow[r0];
  float s1 = smrow[(r0 + 1 < R_) ? r0 + 1 : R_ - 1];
  union { uint4 q; u16 h[8]; } u; u.q = raw;
  #pragma unroll
  for (int j = 0; j < 8; ++j)
    u.h[j] = f2bf(bf2f(u.h[j]) * ((j < bnd) ? s0 : s1));
  return u.q;
}

// ---- GEMM1: P^T[z][n][b] (bf16) = (Xk[256,3840] x (c*WtT)[1536,3840]^T)
// for k-chunk z. Softmax of bij computed per block (its 8 capsules); scale
// applied while staging the B tile into LDS. 128x128 tile, BK=32, 4 waves.
__global__ __launch_bounds__(256) void gemm1(
    const u16* __restrict__ A, const u16* __restrict__ Bt,
    const float* __restrict__ bij, u16* __restrict__ P,
    int kChunk, int kIters) {
  const int K = K1;
  __shared__ u16 As[128 * 32];
  __shared__ u16 Bs[128 * 32];
  __shared__ float sm[8][192];
  int tid = threadIdx.x;
  // --- per-block softmax table: 8 c-groups x 32 lanes, 6 r's per lane
  {
    int cg = tid >> 5, lr = tid & 31;
    int c = (blockIdx.y << 3) + cg;
    float e[6]; float mx = -1e30f;
    #pragma unroll
    for (int j = 0; j < 6; ++j) {
      e[j] = bij[(lr + (j << 5)) * C_ + c];
      mx = fmaxf(mx, e[j]);
    }
    #pragma unroll
    for (int off = 16; off > 0; off >>= 1) mx = fmaxf(mx, __shfl_xor(mx, off));
    float sum = 0.f;
    #pragma unroll
    for (int j = 0; j < 6; ++j) { e[j] = expf(e[j] - mx); sum += e[j]; }
    #pragma unroll
    for (int off = 16; off > 0; off >>= 1) sum += __shfl_xor(sum, off);
    float inv = 1.0f / sum;
    #pragma unroll
    for (int j = 0; j < 6; ++j) sm[cg][lr + (j << 5)] = e[j] * inv;
  }
  __syncthreads();

  long m0 = (long)blockIdx.x * 128, n0 = (long)blockIdx.y * 128;
  int k0 = blockIdx.z * kChunk;
  const u16* Ab = A + m0 * K + k0;
  const u16* Bb = Bt + n0 * K + k0;
  int srow = tid >> 2;              // 0..63 (+64 for second row)
  int scol = (tid & 3) << 3;        // 0,8,16,24
  int w = tid >> 6, lane = tid & 63;
  int wm = (w >> 1) << 6, wn = (w & 1) << 6;
  int quad = lane >> 4, lrow = lane & 15;
  int cl0 = srow >> 4;              // c_local of row srow (0..3)
  floatx4 acc[4][4];
  #pragma unroll
  for (int a = 0; a < 4; ++a)
    #pragma unroll
    for (int b = 0; b < 4; ++b) acc[a][b] = (floatx4){0.f, 0.f, 0.f, 0.f};

  for (int kt = 0; kt < kIters; ++kt) {
    int kk = kt << 5;
    uint4 a0 = *(const uint4*)(Ab + (long)srow * K + kk + scol);
    uint4 a1 = *(const uint4*)(Ab + (long)(srow + 64) * K + kk + scol);
    uint4 b0 = *(const uint4*)(Bb + (long)srow * K + kk + scol);
    uint4 b1 = *(const uint4*)(Bb + (long)(srow + 64) * K + kk + scol);
    int kg = k0 + kk + scol;
    uint4 b0s = scale_b8(b0, kg, &sm[cl0][0]);
    uint4 b1s = scale_b8(b1, kg, &sm[cl0 + 4][0]);
    __syncthreads();
    ((uint4*)As)[tid] = a0;
    ((uint4*)As)[tid + 256] = a1;
    ((uint4*)Bs)[tid] = b0s;
    ((uint4*)Bs)[tid + 256] = b1s;
    __syncthreads();
    short8 af[4], bfr[4];
    #pragma unroll
    for (int ms = 0; ms < 4; ++ms)
      af[ms] = *(const short8*)&As[(wm + ms * 16 + lrow) * 32 + (quad << 3)];
    #pragma unroll
    for (int ns = 0; ns < 4; ++ns)
      bfr[ns] = *(const short8*)&Bs[(wn + ns * 16 + lrow) * 32 + (quad << 3)];
    #pragma unroll
    for (int ms = 0; ms < 4; ++ms)
      #pragma unroll
      for (int ns = 0; ns < 4; ++ns)
        acc[ms][ns] = __builtin_amdgcn_mfma_f32_16x16x32_bf16(
            af[ms], bfr[ns], acc[ms][ns], 0, 0, 0);
  }
  // transposed bf16 store: P[z][n*256 + b]; lane holds 4 consecutive b
  size_t zb = (size_t)blockIdx.z * (size_t)STILE;
  #pragma unroll
  for (int ms = 0; ms < 4; ++ms)
    #pragma unroll
    for (int ns = 0; ns < 4; ++ns) {
      int b = (int)m0 + wm + ms * 16 + (quad << 2);
      int n = (int)n0 + wn + ns * 16 + lrow;
      uint2 pk;
      pk.x = pack2(acc[ms][ns][0], acc[ms][ns][1]);
      pk.y = pack2(acc[ms][ns][2], acc[ms][ns][3]);
      *(uint2*)&P[zb + (size_t)n * B_ + b] = pk;
    }
}

// ---- GEMM2 + agreement fused, K split 2x128 (agreement linear in Z).
__global__ __launch_bounds__(256) void gemm2_agree(
    const u16* __restrict__ A, const u16* __restrict__ Bt,
    const u16* __restrict__ WtT, float* __restrict__ bij) {
  const int K = 256;
  __shared__ u16 As[128 * 32];
  __shared__ u16 Bs[128 * 32];
  int tid = threadIdx.x;
  long m0 = (long)blockIdx.x * 128, n0 = (long)blockIdx.y * 128;
  int k0 = blockIdx.z << 7;
  const u16* Ab = A + m0 * K + k0;
  const u16* Bb = Bt + n0 * K + k0;
  int srow = tid >> 2;
  int scol = (tid & 3) << 3;
  int w = tid >> 6, lane = tid & 63;
  int wm = (w >> 1) << 6, wn = (w & 1) << 6;
  int quad = lane >> 4, lrow = lane & 15;
  floatx4 acc[4][4];
  #pragma unroll
  for (int a = 0; a < 4; ++a)
    #pragma unroll
    for (int b = 0; b < 4; ++b) acc[a][b] = (floatx4){0.f, 0.f, 0.f, 0.f};

  for (int kt = 0; kt < 4; ++kt) {
    int kk = kt << 5;
    uint4 a0 = *(const uint4*)(Ab + (long)srow * K + kk + scol);
    uint4 a1 = *(const uint4*)(Ab + (long)(srow + 64) * K + kk + scol);
    uint4 b0 = *(const uint4*)(Bb + (long)srow * K + kk + scol);
    uint4 b1 = *(const uint4*)(Bb + (long)(srow + 64) * K + kk + scol);
    __syncthreads();
    ((uint4*)As)[tid] = a0;
    ((uint4*)As)[tid + 256] = a1;
    ((uint4*)Bs)[tid] = b0;
    ((uint4*)Bs)[tid + 256] = b1;
    __syncthreads();
    short8 af[4], bfr[4];
    #pragma unroll
    for (int ms = 0; ms < 4; ++ms)
      af[ms] = *(const short8*)&As[(wm + ms * 16 + lrow) * 32 + (quad << 3)];
    #pragma unroll
    for (int ns = 0; ns < 4; ++ns)
      bfr[ns] = *(const short8*)&Bs[(wn + ns * 16 + lrow) * 32 + (quad << 3)];
    #pragma unroll
    for (int ms = 0; ms < 4; ++ms)
      #pragma unroll
      for (int ns = 0; ns < 4; ++ns)
        acc[ms][ns] = __builtin_amdgcn_mfma_f32_16x16x32_bf16(
            af[ms], bfr[ns], acc[ms][ns], 0, 0, 0);
  }
  // epilogue: per fragment, cols = one capsule c; 16 rows span <=2 routes r.
  #pragma unroll
  for (int ms = 0; ms < 4; ++ms) {
    int rowbase = (int)m0 + wm + ms * 16;          // wave-uniform
    int r_lo = rowbase / I_;
    int r_hi = (rowbase + 15) / I_;
    int bnd = (r_lo + 1) * I_;
    int rowl = rowbase + (quad << 2);
    #pragma unroll
    for (int ns = 0; ns < 4; ++ns) {
      int col = (int)n0 + wn + ns * 16 + lrow;
      uint2 wv = *(const uint2*)&WtT[(size_t)col * K1 + rowl];
      u16 h[4];
      h[0] = (u16)(wv.x & 0xffff); h[1] = (u16)(wv.x >> 16);
      h[2] = (u16)(wv.y & 0xffff); h[3] = (u16)(wv.y >> 16);
      float p0 = 0.f, p1 = 0.f;
      #pragma unroll
      for (int e = 0; e < 4; ++e) {
        float pr = acc[ms][ns][e] * bf2f(h[e]);
        if (rowl + e < bnd) p0 += pr; else p1 += pr;
      }
      #pragma unroll
      for (int off = 32; off > 0; off >>= 1) {
        p0 += __shfl_xor(p0, off);
        p1 += __shfl_xor(p1, off);
      }
      if (lane == 0) {
        int c = col >> 4;
        atomicAdd(&bij[r_lo * C_ + c], p0 * (1.0f / 256.0f));
        atomicAdd(&bij[r_hi * C_ + c], p1 * (1.0f / 256.0f));
      }
    }
  }
}

// ---- fused split-K reduce + squash, reading P^T[z][n][b] bf16.
// grid (96 c, 2 b-halves), block 256 = 4 o-groups x 64 lanes; 2 b per lane.
__global__ void k_redsq(const u16* __restrict__ P, float* __restrict__ out,
                        u16* __restrict__ vT, int last) {
  __shared__ float nsq_l[4][128];
  int c = blockIdx.x, bh = blockIdx.y;
  int lane = threadIdx.x & 63, og = threadIdx.x >> 6;
  int bi = (lane << 1);                  // local b index (0..126 step 2)
  int b = (bh << 7) + bi;
  float acc[4][2];
  #pragma unroll
  for (int oo = 0; oo < 4; ++oo) { acc[oo][0] = 0.f; acc[oo][1] = 0.f; }
  for (int z = 0; z < ZSPLIT; ++z) {
    size_t base = (size_t)z * STILE + (size_t)((c << 4) + (og << 2)) * B_ + b;
    #pragma unroll
    for (int oo = 0; oo < 4; ++oo) {
      unsigned int u = *(const unsigned int*)&P[base + (size_t)oo * B_];
      acc[oo][0] += bf2f((u16)(u & 0xffff));
      acc[oo][1] += bf2f((u16)(u >> 16));
    }
  }
  float q0 = 0.f, q1 = 0.f;
  #pragma unroll
  for (int oo = 0; oo < 4; ++oo) {
    q0 += acc[oo][0] * acc[oo][0];
    q1 += acc[oo][1] * acc[oo][1];
  }
  nsq_l[og][bi] = q0;
  nsq_l[og][bi + 1] = q1;
  __syncthreads();
  float n0 = nsq_l[0][bi] + nsq_l[1][bi] + nsq_l[2][bi] + nsq_l[3][bi];
  float n1 = nsq_l[0][bi + 1] + nsq_l[1][bi + 1] + nsq_l[2][bi + 1] + nsq_l[3][bi + 1];
  float f0 = n0 / ((1.0f + n0) * sqrtf(n0));
  float f1 = n1 / ((1.0f + n1) * sqrtf(n1));
  #pragma unroll
  for (int oo = 0; oo < 4; ++oo) { acc[oo][0] *= f0; acc[oo][1] *= f1; }
  if (last) {
    float4 v0 = (float4){acc[0][0], acc[1][0], acc[2][0], acc[3][0]};
    float4 v1 = (float4){acc[0][1], acc[1][1], acc[2][1], acc[3][1]};
    *(float4*)(out + (size_t)b * N_ + (c << 4) + (og << 2)) = v0;
    *(float4*)(out + (size_t)(b + 1) * N_ + (c << 4) + (og << 2)) = v1;
  } else {
    #pragma unroll
    for (int oo = 0; oo < 4; ++oo)
      *(unsigned int*)&vT[(size_t)((c << 4) + (og << 2) + oo) * B_ + b] =
          pack2(acc[oo][0], acc[oo][1]);
  }
}

extern "C" void kernel_launch(void* const* d_in, const int* in_sizes, int n_in,
                              void* d_out, int out_size, void* d_ws, size_t ws_size,
                              hipStream_t stream) {
  const float* X = (const float*)d_in[0];   // fp32 [256,192,20]
  const float* W = (const float*)d_in[1];   // fp32 [192,96,16,20]
  float* out = (float*)d_out;               // fp32 [256,96,16]
  char* ws = (char*)d_ws;
  u16*  WtT = (u16*)(ws);                   // 11,796,480 B
  u16*  Xk  = (u16*)(ws + 11796480);        //  1,966,080 B
  u16*  xT  = (u16*)(ws + 13762560);        //  1,966,080 B
  u16*  vT  = (u16*)(ws + 15728640);        //    786,432 B
  u16*  Pb  = (u16*)(ws + 16515072);        // 20 x 786,432 B = 15,728,640 B
  float* bij = (float*)(ws + 32243712);     //     73,728 B

  k_prep<<<23352, 256, 0, stream>>>(W, X, WtT, Xk, xT, bij);

  for (int it = 0; it < 3; ++it) {
    // s partials: M=256,N=1536,K=3840 split 20 ways (chunk 192 = 6 k-iters);
    // softmax+scale folded in (iter 0: bij==0 -> uniform 1/192 automatically)
    gemm1<<<dim3(2, 12, ZSPLIT), 256, 0, stream>>>(Xk, WtT, bij, Pb, 192, 6);
    k_redsq<<<dim3(96, 2), 256, 0, stream>>>(Pb, out, vT, it == 2);
    if (it < 2)
      gemm2_agree<<<dim3(30, 12, 2), 256, 0, stream>>>(xT, vT, WtT, bij);
  }
}